// Round 14
// baseline (2661.165 us; speedup 1.0000x reference)
//
#include <hip/hip_runtime.h>
#include <stdint.h>

typedef _Float16 f16;
typedef _Float16 f16x8 __attribute__((ext_vector_type(8)));
typedef float f32x4 __attribute__((ext_vector_type(4)));
typedef int   i32x4 __attribute__((ext_vector_type(4)));

#define SEQ   512
#define BATCH 128
#define DIM   512
#define HID   256
#define G4    1024

typedef const __attribute__((address_space(1))) void* gas1p;
typedef __attribute__((address_space(3))) void* las3p;

__device__ __forceinline__ uint32_t pk2(float a, float b){
  return __builtin_bit_cast(uint32_t, __builtin_amdgcn_cvt_pkrtz(a, b));
}
__device__ __forceinline__ float sigm(float x){
  return __builtin_amdgcn_rcpf(1.0f + __expf(-x));
}
__device__ __forceinline__ float tanh_(float x){
  return 1.0f - 2.0f*__builtin_amdgcn_rcpf(__expf(2.0f*x) + 1.0f);
}
__device__ __forceinline__ uint32_t q8pack(float4 v){
  int a = __float2int_rn(v.x*2048.f); a = a > 127 ? 127 : (a < -127 ? -127 : a);
  int b = __float2int_rn(v.y*2048.f); b = b > 127 ? 127 : (b < -127 ? -127 : b);
  int c = __float2int_rn(v.z*2048.f); c = c > 127 ? 127 : (c < -127 ? -127 : c);
  int d = __float2int_rn(v.w*2048.f); d = d > 127 ? 127 : (d < -127 ? -127 : d);
  return (uint32_t)(a & 0xff) | ((uint32_t)(b & 0xff) << 8) |
         ((uint32_t)(c & 0xff) << 16) | ((uint32_t)(d & 0xff) << 24);
}

// ---------------- phase 0: fp32 -> f16 convert ---------------------------------
__global__ void __launch_bounds__(256) cvt_f16_kernel(const float* __restrict__ in,
                                                      f16* __restrict__ out, int n8){
  int i = blockIdx.x*blockDim.x + threadIdx.x;
  if (i >= n8) return;
  const float4* p = (const float4*)in;
  float4 a = p[2*i], b = p[2*i+1];
  uint4 r;
  r.x = pk2(a.x, a.y); r.y = pk2(a.z, a.w);
  r.z = pk2(b.x, b.y); r.w = pk2(b.z, b.w);
  ((uint4*)out)[i] = r;
}

// ---------------- phase 0b: W_hh -> i8 MFMA B-fragments ------------------------
// WB[ci], ci = ((w*8 + nt)*4 + kt)*64 + l : 16 i8 of
// Whh[g][k0..k0+16), g = tau*256 + w*32 + half*16 + (l&15), tau=nt>>1,
// half=nt&1, k0 = kt*64 + (l>>4)*16.  (B col = lane&15, k-contiguous per lane —
// identical convention to the verified f16 GEMM B fragment.)
__global__ void __launch_bounds__(256) prep_whhB(const float* __restrict__ Whh,
                                                 uint4* __restrict__ WB){
  int ci = blockIdx.x*256 + threadIdx.x;       // 0..16383
  int l  = ci & 63;
  int kt = (ci >> 6) & 3;
  int nt = (ci >> 8) & 7;
  int w  = ci >> 11;
  int tau = nt >> 1, half = nt & 1;
  int g  = tau*256 + w*32 + half*16 + (l & 15);
  int k0 = kt*64 + (l >> 4)*16;
  const float* src = Whh + g*HID + k0;
  float4 v0 = *(const float4*)(src);
  float4 v1 = *(const float4*)(src + 4);
  float4 v2 = *(const float4*)(src + 8);
  float4 v3 = *(const float4*)(src + 12);
  WB[ci] = make_uint4(q8pack(v0), q8pack(v1), q8pack(v2), q8pack(v3));
}

// ---------------- phase 1: xg = x . W_ih^T + bias, f16 MFMA --------------------
// Epilogue: PLAIN quad layout (proven r5-r12): C[row*G4 + u*4 + tau],
// u = col&255, tau = col>>8  (each unit's {i,f,g,o} contiguous, 8 bytes).
#define BM 128
#define BN 128
#define BK 64

__global__ void __launch_bounds__(256) gemm_xg_kernel(const f16* __restrict__ A,
                                                      const f16* __restrict__ Bm,
                                                      const float* __restrict__ bih,
                                                      const float* __restrict__ bhh,
                                                      f16* __restrict__ C){
  __shared__ __align__(16) f16 ldsA[BM*BK];
  __shared__ __align__(16) f16 ldsB[BN*BK];
  const int tid  = threadIdx.x;
  const int wave = tid >> 6;
  const int lane = tid & 63;
  const int bid  = blockIdx.x;
  const int nt   = bid & 7;
  const int mt   = bid >> 3;
  const long m0  = (long)mt * BM;
  const int n0   = nt * BN;
  const int wm   = wave >> 1, wn = wave & 1;
  const int lrow = lane >> 3;
  const int lk   = (lane & 7) * 8;

  f32x4 acc[4][4];
  #pragma unroll
  for (int i=0;i<4;++i)
    #pragma unroll
    for (int j=0;j<4;++j) acc[i][j] = (f32x4){0.f,0.f,0.f,0.f};

  auto ldsAq = (__attribute__((address_space(3))) char*)ldsA;
  auto ldsBq = (__attribute__((address_space(3))) char*)ldsB;

  for (int kt = 0; kt < DIM/BK; ++kt){
    const int k0 = kt*BK;
    __syncthreads();
    #pragma unroll
    for (int i = 0; i < 4; ++i){
      const int seg = wave*4 + i;
      const f16* ga = A  + (m0 + seg*8 + lrow)*DIM + (k0 + lk);
      const f16* gb = Bm + (long)(n0 + seg*8 + lrow)*DIM + (k0 + lk);
      __builtin_amdgcn_global_load_lds((gas1p)ga, (las3p)(ldsAq + seg*1024), 16, 0, 0);
      __builtin_amdgcn_global_load_lds((gas1p)gb, (las3p)(ldsBq + seg*1024), 16, 0, 0);
    }
    __syncthreads();
    #pragma unroll
    for (int kk = 0; kk < 2; ++kk){
      f16x8 af[4], bf[4];
      const int kb = kk*32 + (lane>>4)*8;
      #pragma unroll
      for (int mi=0; mi<4; ++mi){
        af[mi] = *(const f16x8*)(ldsA + (wm*64 + mi*16 + (lane&15))*BK + kb);
        bf[mi] = *(const f16x8*)(ldsB + (wn*64 + mi*16 + (lane&15))*BK + kb);
      }
      #pragma unroll
      for (int mi=0;mi<4;++mi)
        #pragma unroll
        for (int ni=0;ni<4;++ni)
          acc[mi][ni] = __builtin_amdgcn_mfma_f32_16x16x32_f16(af[mi], bf[ni], acc[mi][ni], 0,0,0);
    }
  }
  float bias[4];
  #pragma unroll
  for (int ni=0;ni<4;++ni){
    int col = n0 + wn*64 + ni*16 + (lane&15);
    bias[ni] = bih[col] + bhh[col];
  }
  #pragma unroll
  for (int mi=0;mi<4;++mi){
    #pragma unroll
    for (int ni=0;ni<4;++ni){
      int col = n0 + wn*64 + ni*16 + (lane&15);
      int cpos = (col & 255)*4 + (col >> 8);       // plain quad layout
      #pragma unroll
      for (int r=0;r<4;++r){
        long row = m0 + wm*64 + mi*16 + (lane>>4)*4 + r;
        C[row*G4 + cpos] = (f16)(acc[mi][ni][r] + bias[ni]);
      }
    }
  }
}

// ---------------- phase 2: MFMA LSTM, B-fragments pinned in AGPRs --------------
// 8 blocks x 512 thr (8 waves, 2/SIMD). Block bb: batch rows [16bb,16bb+16).
// Wave w: units [32w,32w+32) = 8 N-tiles (tau*2+half) x 4 K-tiles of builtin
// i8 16x16x64 MFMA. 32 B-frags (128 regs) pinned in AGPRs by per-iteration
// "+a" keep-alives; VGPR-class demand ~115 (inside RA's keep zone). h: i8
// [2][16][256] LDS double buffer, XOR-swizzled 16B groups (2-way conflicts).
// xg: direct per-lane global uint2 loads, double-buffered in NAMED reg sets.
// ONE barrier per step.
__global__ void
__attribute__((amdgpu_flat_work_group_size(512, 512), amdgpu_waves_per_eu(2, 2)))
lstm_mfma(const f16* __restrict__ xq,
          const uint4* __restrict__ WB,
          const float* __restrict__ fcw,
          const float* __restrict__ fcb,
          float* __restrict__ out){
  __shared__ __align__(16) char H8[2][4096];   // [buf][rb*256 + swz]
  __shared__ float harr[16*256];               // final h (f32) for FC
  __shared__ float part[16*32];
  const int t  = threadIdx.x;
  const int bb = blockIdx.x;
  const int l  = t & 63, w = t >> 6;
  const int col = l & 15, lg = l >> 4;
  const float invS = 1.0f / (2048.0f * 127.0f);

  // ---- B-fragments (live whole kernel; pinned via "+a" in-loop keep-alives)
  i32x4 Bf[32];
  {
    const uint4* wp = WB + (size_t)w*2048;
    #pragma unroll
    for (int i = 0; i < 32; ++i)
      Bf[i] = __builtin_bit_cast(i32x4, wp[i*64 + l]);
  }

  ((uint4*)H8)[t] = make_uint4(0,0,0,0);       // zero both h buffers (8192 B)

  float cst[8];
  #pragma unroll
  for (int i=0;i<8;++i) cst[i] = 0.f;

  const f16* xb = xq + (long)(16*bb)*512*G4;

  // xg register double buffer: xv[reg][half] quads, NAMED sets A and B
  uint2 xA0,xA1,xA2,xA3,xA4,xA5,xA6,xA7, xB0,xB1,xB2,xB3,xB4,xB5,xB6,xB7;
  #define XLOAD(vv, ts1) do { \
    const f16* base_ = xb + (long)(ts1)*G4; \
    vv##0 = *(const uint2*)(base_ + ((4*lg+0)*512)*(long)G4 + (w*32+ 0+col)*4); \
    vv##1 = *(const uint2*)(base_ + ((4*lg+0)*512)*(long)G4 + (w*32+16+col)*4); \
    vv##2 = *(const uint2*)(base_ + ((4*lg+1)*512)*(long)G4 + (w*32+ 0+col)*4); \
    vv##3 = *(const uint2*)(base_ + ((4*lg+1)*512)*(long)G4 + (w*32+16+col)*4); \
    vv##4 = *(const uint2*)(base_ + ((4*lg+2)*512)*(long)G4 + (w*32+ 0+col)*4); \
    vv##5 = *(const uint2*)(base_ + ((4*lg+2)*512)*(long)G4 + (w*32+16+col)*4); \
    vv##6 = *(const uint2*)(base_ + ((4*lg+3)*512)*(long)G4 + (w*32+ 0+col)*4); \
    vv##7 = *(const uint2*)(base_ + ((4*lg+3)*512)*(long)G4 + (w*32+16+col)*4); \
  } while(0)

  XLOAD(xA, 0);                                // step-0 gate quads
  __syncthreads();

  #define STEP(ts, XC, XN) do { \
    const int cur_ = (ts) & 1, nxt_ = cur_ ^ 1; \
    i32x4 Af[4]; \
    _Pragma("unroll") \
    for (int kt = 0; kt < 4; ++kt) \
      Af[kt] = *(const i32x4*)(&H8[cur_][col*256 + (((4*kt+lg) ^ (col & 7)) << 4)]); \
    if ((ts) + 1 < SEQ) { XLOAD(XN, (ts)+1); } \
    _Pragma("unroll") \
    for (int i = 0; i < 32; ++i) asm volatile("" : "+a"(Bf[i])); \
    i32x4 Cf[8]; \
    _Pragma("unroll") \
    for (int i = 0; i < 8; ++i) Cf[i] = (i32x4){0,0,0,0}; \
    _Pragma("unroll") \
    for (int kt = 0; kt < 4; ++kt) \
      _Pragma("unroll") \
      for (int nt = 0; nt < 8; ++nt) \
        Cf[nt] = __builtin_amdgcn_mfma_i32_16x16x64_i8(Af[kt], Bf[nt*4+kt], Cf[nt], 0, 0, 0); \
    uint2 xvs[8] = {XC##0,XC##1,XC##2,XC##3,XC##4,XC##5,XC##6,XC##7}; \
    _Pragma("unroll") \
    for (int reg = 0; reg < 4; ++reg){ \
      const int rb_ = 4*lg + reg; \
      _Pragma("unroll") \
      for (int half = 0; half < 2; ++half){ \
        uint2 xv = xvs[reg*2 + half]; \
        float xi = (float)__builtin_bit_cast(f16, (unsigned short)(xv.x & 0xffff)); \
        float xf = (float)__builtin_bit_cast(f16, (unsigned short)(xv.x >> 16)); \
        float xg_= (float)__builtin_bit_cast(f16, (unsigned short)(xv.y & 0xffff)); \
        float xo = (float)__builtin_bit_cast(f16, (unsigned short)(xv.y >> 16)); \
        float gi = xi  + (float)Cf[0*2+half][reg]*invS; \
        float gf = xf  + (float)Cf[1*2+half][reg]*invS; \
        float gg = xg_ + (float)Cf[2*2+half][reg]*invS; \
        float go = xo  + (float)Cf[3*2+half][reg]*invS; \
        const int si = half*4 + reg; \
        float cv = sigm(gf)*cst[si] + sigm(gi)*tanh_(gg); \
        cst[si] = cv; \
        float hv = sigm(go)*tanh_(cv); \
        *(int8_t*)(&H8[nxt_][rb_*256 + (((2*w + half) ^ (rb_ & 7)) << 4) + col]) \
            = (int8_t)__float2int_rn(hv * 127.f); \
        if ((ts) == SEQ-1) harr[rb_*256 + w*32 + half*16 + col] = hv; \
      } \
    } \
    __syncthreads(); \
  } while(0)

  for (int ts = 0; ts < SEQ; ts += 2){
    STEP(ts,   xA, xB);
    STEP(ts+1, xB, xA);
  }
  #undef STEP
  #undef XLOAD

  // ---- fused FC head: out[16bb+rb] = h[rb] . fcw + fcb
  {
    int rbq = t >> 5, seg = t & 31;
    float s = 0.f;
    #pragma unroll
    for (int j2 = 0; j2 < 8; ++j2)
      s += harr[rbq*256 + seg*8 + j2] * fcw[seg*8 + j2];
    part[rbq*32 + seg] = s;
  }
  __syncthreads();
  if (t < 16){
    float s = 0.f;
    #pragma unroll
    for (int k = 0; k < 32; ++k) s += part[t*32 + k];
    out[16*bb + t] = s + fcb[0];
  }
}

extern "C" void kernel_launch(void* const* d_in, const int* in_sizes, int n_in,
                              void* d_out, int out_size, void* d_ws, size_t ws_size,
                              hipStream_t stream) {
  const float* x   = (const float*)d_in[0];
  const float* Wih = (const float*)d_in[1];
  const float* Whh = (const float*)d_in[2];
  const float* bih = (const float*)d_in[3];
  const float* bhh = (const float*)d_in[4];
  const float* fcw = (const float*)d_in[5];
  const float* fcb = (const float*)d_in[6];
  float* out = (float*)d_out;

  char* ws = (char*)d_ws;
  f16*   xh = (f16*)ws;                                    //  67,108,864 B
  f16*   Wh = (f16*)(ws + 67108864);                       //   1,048,576 B
  f16*   xq = (f16*)(ws + 68157440);                       // 134,217,728 B
  uint4* WB = (uint4*)(ws + 202375168);                    //     262,144 B

  cvt_f16_kernel<<<16384, 256, 0, stream>>>(x,   xh, 33554432/8);
  cvt_f16_kernel<<<256,   256, 0, stream>>>(Wih, Wh, 524288/8);
  prep_whhB<<<64, 256, 0, stream>>>(Whh, WB);
  gemm_xg_kernel<<<4096, 256, 0, stream>>>(xh, Wh, bih, bhh, xq);
  lstm_mfma<<<8, 512, 0, stream>>>(xq, WB, fcw, fcb, out);
}

// Round 15
// 1062.538 us; speedup vs baseline: 2.5045x; 2.5045x over previous
//
#include <hip/hip_runtime.h>
#include <stdint.h>

typedef _Float16 f16;
typedef _Float16 f16x8 __attribute__((ext_vector_type(8)));
typedef float f32x4 __attribute__((ext_vector_type(4)));

#define SEQ   512
#define BATCH 128
#define DIM   512
#define HID   256
#define G4    1024

typedef const __attribute__((address_space(1))) void* gas1p;
typedef __attribute__((address_space(3))) void* las3p;

__device__ __forceinline__ uint32_t pk2(float a, float b){
  return __builtin_bit_cast(uint32_t, __builtin_amdgcn_cvt_pkrtz(a, b));
}

__device__ __forceinline__ int sdot4(uint32_t a, uint32_t b, int c){
#if __has_builtin(__builtin_amdgcn_sdot4)
  return __builtin_amdgcn_sdot4(a, b, c, false);
#else
  int s = c;
  #pragma unroll
  for (int i = 0; i < 4; ++i){
    int ai = (int)(signed char)((a >> (8*i)) & 0xff);
    int bi = (int)(signed char)((b >> (8*i)) & 0xff);
    s += ai*bi;
  }
  return s;
#endif
}

__device__ __forceinline__ int dotq(uint4 w, uint4 h, int acc){
  acc = sdot4(w.x, h.x, acc);
  acc = sdot4(w.y, h.y, acc);
  acc = sdot4(w.z, h.z, acc);
  acc = sdot4(w.w, h.w, acc);
  return acc;
}

__device__ __forceinline__ float sigm(float x){
  return __builtin_amdgcn_rcpf(1.0f + __expf(-x));
}
__device__ __forceinline__ float tanh_(float x){
  return 1.0f - 2.0f*__builtin_amdgcn_rcpf(__expf(2.0f*x) + 1.0f);
}
__device__ __forceinline__ uint32_t q8pack(float4 v){
  int a = __float2int_rn(v.x*2048.f); a = a > 127 ? 127 : (a < -127 ? -127 : a);
  int b = __float2int_rn(v.y*2048.f); b = b > 127 ? 127 : (b < -127 ? -127 : b);
  int c = __float2int_rn(v.z*2048.f); c = c > 127 ? 127 : (c < -127 ? -127 : c);
  int d = __float2int_rn(v.w*2048.f); d = d > 127 ? 127 : (d < -127 ? -127 : d);
  return (uint32_t)(a & 0xff) | ((uint32_t)(b & 0xff) << 8) |
         ((uint32_t)(c & 0xff) << 16) | ((uint32_t)(d & 0xff) << 24);
}

// ---------------- phase 0: fp32 -> f16 convert (vectorized, 8 elems/thread) ----
__global__ void __launch_bounds__(256) cvt_f16_kernel(const float* __restrict__ in,
                                                      f16* __restrict__ out, int n8){
  int i = blockIdx.x*blockDim.x + threadIdx.x;
  if (i >= n8) return;
  const float4* p = (const float4*)in;
  float4 a = p[2*i], b = p[2*i+1];
  uint4 r;
  r.x = pk2(a.x, a.y); r.y = pk2(a.z, a.w);
  r.z = pk2(b.x, b.y); r.w = pk2(b.z, b.w);
  ((uint4*)out)[i] = r;
}

// ---------------- phase 0b: W_hh -> i8 quads, THREE stream layouts -------------
// Thread t (0..511): lane=t&63, j=(t>>6)*32+(lane&31), khalf=lane>>5.
// Row r (0..3) -> gate row g = j + r*256.  Quad Q (0..7): k words
// khalf*32 + Q*4 .. +4 (16 k-elements).  Destinations:
//   Q 0,1 -> WR[(r*2+Q  )*512 + t]   (register-resident, 32 w/thread)
//   Q 2,3 -> WLg[(r*2+Q-2)*512 + t]  (staged to 64KB LDS slab)
//   Q 4..7-> WG[(r*4+Q-4)*512 + t]   (streamed from shared L2)
__global__ void __launch_bounds__(256) prep_whh8(const float* __restrict__ Whh,
                                                 uint4* __restrict__ WR,
                                                 uint4* __restrict__ WLg,
                                                 uint4* __restrict__ WG){
  int tid = blockIdx.x*256 + threadIdx.x;      // 0..16383
  int t  = tid & 511;
  int qi = tid >> 9;                           // 0..31
  int r  = qi >> 3, Q = qi & 7;
  int lane  = t & 63;
  int j     = (t >> 6)*32 + (lane & 31);
  int khalf = lane >> 5;
  int g  = j + (r << 8);
  int kw = khalf*32 + Q*4;
  const float* src = Whh + g*HID + kw*4;
  float4 v0 = *(const float4*)(src);
  float4 v1 = *(const float4*)(src + 4);
  float4 v2 = *(const float4*)(src + 8);
  float4 v3 = *(const float4*)(src + 12);
  uint4 pk = make_uint4(q8pack(v0), q8pack(v1), q8pack(v2), q8pack(v3));
  if (Q < 2)      WR [(r*2 + Q    )*512 + t] = pk;
  else if (Q < 4) WLg[(r*2 + Q - 2)*512 + t] = pk;
  else            WG [(r*4 + Q - 4)*512 + t] = pk;
}

// ---------------- phase 1: xg = x . W_ih^T + bias, f16 MFMA --------------------
// Epilogue QUAD layout: for gate col g, unit u=g&255, tau=g>>8:
// C[m*1024 + u*4 + tau]  (each unit's {i,f,g,o} contiguous f16x4).
#define BM 128
#define BN 128
#define BK 64

__global__ void __launch_bounds__(256) gemm_xg_kernel(const f16* __restrict__ A,
                                                      const f16* __restrict__ Bm,
                                                      const float* __restrict__ bih,
                                                      const float* __restrict__ bhh,
                                                      f16* __restrict__ C){
  __shared__ __align__(16) f16 ldsA[BM*BK];
  __shared__ __align__(16) f16 ldsB[BN*BK];
  const int tid  = threadIdx.x;
  const int wave = tid >> 6;
  const int lane = tid & 63;
  const int bid  = blockIdx.x;
  const int nt   = bid & 7;
  const int mt   = bid >> 3;
  const long m0  = (long)mt * BM;
  const int n0   = nt * BN;
  const int wm   = wave >> 1, wn = wave & 1;
  const int lrow = lane >> 3;
  const int lk   = (lane & 7) * 8;

  f32x4 acc[4][4];
  #pragma unroll
  for (int i=0;i<4;++i)
    #pragma unroll
    for (int j=0;j<4;++j) acc[i][j] = (f32x4){0.f,0.f,0.f,0.f};

  auto ldsAq = (__attribute__((address_space(3))) char*)ldsA;
  auto ldsBq = (__attribute__((address_space(3))) char*)ldsB;

  for (int kt = 0; kt < DIM/BK; ++kt){
    const int k0 = kt*BK;
    __syncthreads();
    #pragma unroll
    for (int i = 0; i < 4; ++i){
      const int seg = wave*4 + i;
      const f16* ga = A  + (m0 + seg*8 + lrow)*DIM + (k0 + lk);
      const f16* gb = Bm + (long)(n0 + seg*8 + lrow)*DIM + (k0 + lk);
      __builtin_amdgcn_global_load_lds((gas1p)ga, (las3p)(ldsAq + seg*1024), 16, 0, 0);
      __builtin_amdgcn_global_load_lds((gas1p)gb, (las3p)(ldsBq + seg*1024), 16, 0, 0);
    }
    __syncthreads();
    #pragma unroll
    for (int kk = 0; kk < 2; ++kk){
      f16x8 af[4], bf[4];
      const int kb = kk*32 + (lane>>4)*8;
      #pragma unroll
      for (int mi=0; mi<4; ++mi){
        af[mi] = *(const f16x8*)(ldsA + (wm*64 + mi*16 + (lane&15))*BK + kb);
        bf[mi] = *(const f16x8*)(ldsB + (wn*64 + mi*16 + (lane&15))*BK + kb);
      }
      #pragma unroll
      for (int mi=0;mi<4;++mi)
        #pragma unroll
        for (int ni=0;ni<4;++ni)
          acc[mi][ni] = __builtin_amdgcn_mfma_f32_16x16x32_f16(af[mi], bf[ni], acc[mi][ni], 0,0,0);
    }
  }
  float bias[4];
  #pragma unroll
  for (int ni=0;ni<4;++ni){
    int col = n0 + wn*64 + ni*16 + (lane&15);
    bias[ni] = bih[col] + bhh[col];
  }
  #pragma unroll
  for (int mi=0;mi<4;++mi){
    #pragma unroll
    for (int ni=0;ni<4;++ni){
      int col = n0 + wn*64 + ni*16 + (lane&15);
      int cpos = (col & 255)*4 + (col >> 8);       // quad layout
      #pragma unroll
      for (int r=0;r<4;++r){
        long row = m0 + wm*64 + mi*16 + (lane>>4)*4 + r;
        C[row*G4 + cpos] = (f16)(acc[mi][ni][r] + bias[ni]);
      }
    }
  }
}

// ---------------- phase 2: sequential LSTM (i8 dot4), balanced 3-stream --------
// r7 geometry: 128 blocks x 512 thr (8 waves, 2/SIMD). Lanes l, l^32 share
// unit j = wave*32+(lane&31); each holds one k-half of all 4 gate rows.
// Per row 8 quads: 2 in registers (wr[8], r12-proven resident), 2 from a 64KB
// LDS slab (8 b128/thread/step), 4 streamed from SHARED L2 (16 loads/thread/
// step; same 128KB for all blocks -> L2-resident). Anti-LICM opaque asm keeps
// the streams in-loop (r12-proven: prevents the hoist->spill disaster).
// Partials via shfl_xor(32); ONE barrier/step; h: i8[2][256] LDS double buffer.
__global__ void
__attribute__((amdgpu_flat_work_group_size(512, 512)))
lstm8_kernel(const f16* __restrict__ xq,
             const uint4* __restrict__ WR,
             const uint4* __restrict__ WLg,
             const uint4* __restrict__ WG,
             const float* __restrict__ fcw,
             const float* __restrict__ fcb,
             float* __restrict__ out){
  extern __shared__ __align__(16) char smem[];
  uint4*   WL  = (uint4*)smem;                 // 4096 uint4 = 64 KiB
  uint8_t* h8  = (uint8_t*)(smem + 65536);     // [2][256] i8 h double buffer
  float*   red = (float*)(smem + 66048);       // 256 f32 reduce
  const int t = threadIdx.x;
  const int b = blockIdx.x;
  const int lane  = t & 63;
  const int j     = (t >> 6)*32 + (lane & 31);
  const int khalf = lane >> 5;
  const float invS = 1.0f / (2048.0f * 127.0f);

  // stage LDS slab (coalesced, one-time): 8 quads/thread
  #pragma unroll
  for (int i = 0; i < 8; ++i) WL[i*512 + t] = WLg[i*512 + t];

  // register weights: quads Q=0,1 x rows 0..3 = 8 uint4 = 32 words
  uint4 wr[8];
  {
    #pragma unroll
    for (int i = 0; i < 8; ++i) wr[i] = WR[i*512 + t];
  }

  if (t < 128) ((uint32_t*)h8)[t] = 0;         // zero both h buffers

  const f16* xrow = xq + (long)b * SEQ * G4;
  ushort4 xv = *(const ushort4*)(xrow + j*4);  // unit quad {i,f,g,o}
  float c = 0.f, hlast = 0.f;
  uintptr_t wga = (uintptr_t)WG;
  __syncthreads();

  for (int ts = 0; ts < SEQ; ++ts){
    ushort4 xc = xv;
    if (ts + 1 < SEQ) xv = *(const ushort4*)(xrow + (ts+1)*G4 + j*4);

    uint32_t wlo = 0;
    asm("" : "+v"(wlo));                       // opaque: defeats LICM on WL
    asm("" : "+v"(wga));                       // opaque: defeats LICM on WG
    const uint4* wgp = (const uint4*)wga;
    const uint4* hq = (const uint4*)&h8[(ts & 1)*256 + khalf*128];
    uint4 hv[8];
    #pragma unroll
    for (int q = 0; q < 8; ++q) hv[q] = hq[q]; // 2-addr broadcast reads (free)

    int acc[4];
    #pragma unroll
    for (int r = 0; r < 4; ++r){
      int a = 0;
      a = dotq(wr[r*2 + 0], hv[0], a);         // reg quads (Q0,Q1)
      a = dotq(wr[r*2 + 1], hv[1], a);
      a = dotq(WL[wlo + (r*2+0)*512 + t], hv[2], a);   // LDS quads (Q2,Q3)
      a = dotq(WL[wlo + (r*2+1)*512 + t], hv[3], a);
      #pragma unroll
      for (int qg = 0; qg < 4; ++qg)           // L2 quads (Q4..Q7)
        a = dotq(wgp[(r*4+qg)*512 + t], hv[4+qg], a);
      acc[r] = a;
    }
    // combine k-halves within the wave (lanes l <-> l^32), no barrier
    #pragma unroll
    for (int r = 0; r < 4; ++r) acc[r] += __shfl_xor(acc[r], 32);

    // activations (both halves compute identically; duplication is free)
    f16 xi  = __builtin_bit_cast(f16, xc.x), xf = __builtin_bit_cast(f16, xc.y);
    f16 xg_ = __builtin_bit_cast(f16, xc.z), xo = __builtin_bit_cast(f16, xc.w);
    float gi = (float)xi  + (float)acc[0]*invS;
    float gf = (float)xf  + (float)acc[1]*invS;
    float gg = (float)xg_ + (float)acc[2]*invS;
    float go = (float)xo  + (float)acc[3]*invS;
    float iv = sigm(gi), fv = sigm(gf), gv = tanh_(gg), ov = sigm(go);
    c     = fv*c + iv*gv;
    hlast = ov * tanh_(c);
    int hq8 = __float2int_rn(hlast * 127.f);
    if (khalf == 0) h8[((ts+1) & 1)*256 + j] = (uint8_t)(hq8 & 0xff);
    __syncthreads();                           // ONE barrier per step
  }

  // ---- fused FC head
  if (khalf == 0) red[j] = hlast * fcw[j];
  __syncthreads();
  if (t < 64){
    float s = red[t] + red[t+64] + red[t+128] + red[t+192];
    #pragma unroll
    for (int off = 32; off; off >>= 1) s += __shfl_down(s, off);
    if (t == 0) out[b] = s + fcb[0];
  }
}

extern "C" void kernel_launch(void* const* d_in, const int* in_sizes, int n_in,
                              void* d_out, int out_size, void* d_ws, size_t ws_size,
                              hipStream_t stream) {
  const float* x   = (const float*)d_in[0];
  const float* Wih = (const float*)d_in[1];
  const float* Whh = (const float*)d_in[2];
  const float* bih = (const float*)d_in[3];
  const float* bhh = (const float*)d_in[4];
  const float* fcw = (const float*)d_in[5];
  const float* fcb = (const float*)d_in[6];
  float* out = (float*)d_out;

  char* ws = (char*)d_ws;
  f16*   xh  = (f16*)ws;                                   //  67,108,864 B
  f16*   Wh  = (f16*)(ws + 67108864);                      //   1,048,576 B
  f16*   xq  = (f16*)(ws + 68157440);                      // 134,217,728 B
  uint4* WR  = (uint4*)(ws + 202375168);                   //      65,536 B
  uint4* WLg = (uint4*)(ws + 202440704);                   //      65,536 B
  uint4* WG  = (uint4*)(ws + 202506240);                   //     131,072 B

  cvt_f16_kernel<<<16384, 256, 0, stream>>>(x,   xh, 33554432/8);
  cvt_f16_kernel<<<256,   256, 0, stream>>>(Wih, Wh, 524288/8);
  prep_whh8<<<64, 256, 0, stream>>>(Whh, WR, WLg, WG);
  gemm_xg_kernel<<<4096, 256, 0, stream>>>(xh, Wh, bih, bhh, xq);
  (void)hipFuncSetAttribute(reinterpret_cast<const void*>(lstm8_kernel),
                            hipFuncAttributeMaxDynamicSharedMemorySize, 67072);
  lstm8_kernel<<<BATCH, 512, 67072, stream>>>(xq, WR, WLg, WG, fcw, fcb, out);
}